// Round 9
// baseline (9844.342 us; speedup 1.0000x reference)
//
#include <hip/hip_runtime.h>
#include <cstdint>
#include <cstddef>

// ---------------------------------------------------------------------------
// BiLSTM-CRF (NER) for MI355X.
//   1. ingemm_kernel : Gin[dir][t][2048] = emb[sent]@Wih.T + bih + bhh
//   2. lstm_kernel   : chunked recurrence v6 — latency-hiding interleave.
//      R4-R8 lesson: wall = rounds x (L + W); L ~7us (LLC publish->poll->
//      gather; XCD-invariant since agent scope homes at LLC), W ~2-3us.
//      Lever: period = max(I*W, L+W) -> pick I=4 chunks per WG-slot and
//      cut rounds 320 -> 128 (NCH=64/dir, CSTEP=WARM=64).
//      128 chains x 8 WGs / 4 phases = 256 WGs x 512thr, 1 WG/CU.
//      Per phase (ONE barrier): per-wave poll of its source WG's flag ->
//      gather 64 h -> vmcnt drain -> barrier -> publish PREVIOUS phase's
//      flag -> dot (bf16-packed weights, 4 gate rows of one unit/thread) ->
//      butterfly over col-groups (lane gets all 4 gate sums of its unit) ->
//      gates in-lane -> store h (lanes 0-7/wave). No LDS sums, no wave-0
//      bottleneck. Deadlock-free: flag(c,ls) published at (ls,c+1)-barrier;
//      wait(c,ls) depends on strictly lex-smaller positions.
//   3. feats_kernel  : feats[t][32] = concat(hf,hb) @ W_tag.T + b_tag
//   4. Viterbi as associative max-plus block scan (unchanged from R2).
// ---------------------------------------------------------------------------

#define S_LEN 4096
#define E_DIM 300
#define HALF  512
#define G4    2048
#define TAGS  32
#define ALLT  34
#define START_T 32
#define STOP_T  33
#define NEGV  (-10000.0f)
#define VL    64
#define VB    64
#define NCH   64     // chunks per direction
#define WARM  64     // warm-up steps (chunk 0: none)
#define CSTEP (S_LEN / NCH)          // 64 exact steps per chunk
#define CLEN  (WARM + CSTEP)         // 128 rounds
#define NPH   4                      // chunks (phases) per WG-slot
#define WPC   8                      // WGs per chain
#define NCHAINS 128

// ---------------- phase 1: embedding gather + input GEMM -------------------
#define KC 20
__global__ __launch_bounds__(256) void ingemm_kernel(
    const int* __restrict__ sent, const float* __restrict__ emb,
    const float* __restrict__ Wih_f, const float* __restrict__ bih_f, const float* __restrict__ bhh_f,
    const float* __restrict__ Wih_b, const float* __restrict__ bih_b, const float* __restrict__ bhh_b,
    float* __restrict__ Gin)
{
  __shared__ float As[64][KC + 1];
  __shared__ float Bs[64][KC + 1];
  __shared__ int sidx[64];
  const int tid = threadIdx.x;
  const int t0 = blockIdx.x * 64;
  const int J0 = blockIdx.y * 64;
  const int dir = J0 >> 11;
  const int row0 = J0 & 2047;
  const float* __restrict__ Wsrc = dir ? Wih_b : Wih_f;
  const float* __restrict__ bi = dir ? bih_b : bih_f;
  const float* __restrict__ bh = dir ? bhh_b : bhh_f;
  if (tid < 64) sidx[tid] = sent[t0 + tid];
  __syncthreads();
  float acc[4][4] = {};
  const int ty = tid >> 4, tx = tid & 15;
  for (int kk = 0; kk < E_DIM; kk += KC) {
#pragma unroll
    for (int n = 0; n < 5; ++n) {
      int idx = n * 256 + tid;
      int i = idx / KC, k = idx - i * KC;
      As[i][k] = emb[(size_t)sidx[i] * E_DIM + kk + k];
      Bs[i][k] = Wsrc[(size_t)(row0 + i) * E_DIM + kk + k];
    }
    __syncthreads();
#pragma unroll
    for (int k = 0; k < KC; ++k) {
      float a0 = As[ty * 4 + 0][k], a1 = As[ty * 4 + 1][k];
      float a2 = As[ty * 4 + 2][k], a3 = As[ty * 4 + 3][k];
      float b0 = Bs[tx * 4 + 0][k], b1 = Bs[tx * 4 + 1][k];
      float b2 = Bs[tx * 4 + 2][k], b3 = Bs[tx * 4 + 3][k];
      acc[0][0] += a0 * b0; acc[0][1] += a0 * b1; acc[0][2] += a0 * b2; acc[0][3] += a0 * b3;
      acc[1][0] += a1 * b0; acc[1][1] += a1 * b1; acc[1][2] += a1 * b2; acc[1][3] += a1 * b3;
      acc[2][0] += a2 * b0; acc[2][1] += a2 * b1; acc[2][2] += a2 * b2; acc[2][3] += a2 * b3;
      acc[3][0] += a3 * b0; acc[3][1] += a3 * b1; acc[3][2] += a3 * b2; acc[3][3] += a3 * b3;
    }
    __syncthreads();
  }
#pragma unroll
  for (int r = 0; r < 4; ++r)
#pragma unroll
    for (int cc = 0; cc < 4; ++cc) {
      int t = t0 + ty * 4 + r;
      int row = row0 + tx * 4 + cc;
      Gin[((size_t)dir * S_LEN + t) * G4 + row] = acc[r][cc] + bi[row] + bh[row];
    }
}

// ---------------- phase 2: interleaved chunked BiLSTM ----------------------
__device__ __forceinline__ unsigned int bf16r(float x) {   // RNE f32->bf16
  unsigned int u = __float_as_uint(x);
  return (u + 0x7fffu + ((u >> 16) & 1u)) >> 16;
}
__device__ __forceinline__ unsigned int bfpack(float a, float b) {
  return bf16r(a) | (bf16r(b) << 16);
}
__device__ __forceinline__ float bflo(unsigned int p) { return __uint_as_float(p << 16); }
__device__ __forceinline__ float bfhi(unsigned int p) { return __uint_as_float(p & 0xffff0000u); }

// 256 WGs x 512 thr. slot s = wg>>3 (dir = s>>4, chunk base sp = s&15);
// wgd = wg&7 owns units [64*wgd, +64). Thread (wv, lane): rg=lane&7,
// cg=lane>>3; unit u = wv*8+rg; owns the 4 gate rows of u, cols [cg*64,+64)
// as 128 packed bf16. Butterfly over cg (masks 8/16/32) -> every lane holds
// its unit's 4 gate sums. Phase c serves chunk sp+16c (same dir, same pk).
__global__ __attribute__((amdgpu_flat_work_group_size(512, 512),
                          amdgpu_waves_per_eu(2, 2)))
void lstm_kernel(
    const float* __restrict__ Whh_f, const float* __restrict__ Whh_b,
    const float* __restrict__ h0, const float* __restrict__ c0,
    const float* __restrict__ Gin, float* __restrict__ hs,
    float* __restrict__ hwarm, unsigned char* __restrict__ flagsB)
{
  const int wg = blockIdx.x;          // 0..255
  const int s = wg >> 3;              // slot 0..31
  const int wgd = wg & 7;             // producer index within chain
  const int dir = s >> 4;
  const int sp = s & 15;              // chunk base; phase c -> chunk sp+16c
  const int tid = threadIdx.x;
  const int wv = tid >> 6;            // 0..7
  const int lane = tid & 63;
  const int rg = lane & 7;
  const int cg = lane >> 3;           // col group (64 cols)
  const int u = wv * 8 + rg;          // unit in [0,64)
  const float* __restrict__ Whh = dir ? Whh_b : Whh_f;

  // pack this thread's 4 gate rows x 64 cols fp32 -> bf16 pairs (128 VGPRs)
  unsigned int pk[4][32];
#pragma unroll
  for (int r = 0; r < 4; ++r) {
    const float4* wp = (const float4*)(Whh + (size_t)(r * HALF + wgd * 64 + u) * HALF + cg * 64);
#pragma unroll
    for (int i = 0; i < 16; ++i) {
      float4 w = wp[i];
      pk[r][2 * i]     = bfpack(w.x, w.y);
      pk[r][2 * i + 1] = bfpack(w.z, w.w);
    }
  }

  __shared__ __align__(16) float hbuf[NPH][8 * 68];   // skew +4/64: no bank conflicts

  float cst[NPH];
#pragma unroll
  for (int c = 0; c < NPH; ++c) cst[c] = 0.f;
  if (sp == 0) cst[0] = c0[dir * HALF + wgd * 64 + u];

  float* hs_d = hs + (size_t)dir * S_LEN * HALF;
  const float* Gin_d = Gin + (size_t)dir * S_LEN * G4;

  unsigned char* pend = nullptr;      // flag to publish after next barrier

  for (int ls = 0; ls < CLEN; ++ls) {
#pragma unroll
    for (int c = 0; c < NPH; ++c) {
      const int chc = sp + 16 * c;
      const int Wcc = (chc == 0) ? 0 : WARM;
      const int nstc = Wcc + CSTEP;
      if (ls >= nstc) continue;       // WG-uniform: whole phase (and barrier) skipped
      const int chain = dir * 64 + chc;
      unsigned char* flg = flagsB + (size_t)chain * CLEN * WPC;
      float* wbuf = hwarm + (size_t)chain * 2 * HALF;
      const int sg = chc * CSTEP - Wcc + ls;
      const int t = dir ? (S_LEN - 1 - sg) : sg;
      // gin prefetch: the 4 gate rows of unit u (independent of h)
      const float* gp = Gin_d + (size_t)t * G4 + wgd * 64 + u;
      float gin0 = gp[0], gin1 = gp[HALF], gin2 = gp[2 * HALF], gin3 = gp[3 * HALF];
      // per-wave poll: wave wv consumes WG wv's slice -> poll its flag only
      if (ls > 0 && lane == 0) {
        const unsigned char* fb = flg + (size_t)(ls - 1) * WPC + wv;
        while (__hip_atomic_load(fb, __ATOMIC_ACQUIRE, __HIP_MEMORY_SCOPE_AGENT) == 0)
          __builtin_amdgcn_s_sleep(1);
      }
      // gather slice [wv*64, +64)
      float hv;
      if (ls == 0) {
        hv = (chc == 0) ? h0[dir * HALF + wv * 64 + lane] : 0.f;
      } else {
        const float* hsrc = (ls <= Wcc)
            ? (wbuf + ((ls - 1) & 1) * HALF)
            : (hs_d + (size_t)(dir ? t + 1 : t - 1) * HALF);
        hv = __hip_atomic_load(&hsrc[wv * 64 + lane], __ATOMIC_RELAXED, __HIP_MEMORY_SCOPE_AGENT);
      }
      hbuf[c][wv * 68 + lane] = hv;
      // drain this wave's prior h-store (+ gathers) before the barrier so the
      // deferred flag publish below is valid for ALL waves' stores.
      asm volatile("s_waitcnt vmcnt(0)" ::: "memory");
      __syncthreads();
      if (pend) {
        if (tid == 0)
          __hip_atomic_store(pend, (unsigned char)1, __ATOMIC_RELAXED, __HIP_MEMORY_SCOPE_AGENT);
        pend = nullptr;
      }
      // dot: 4 gate rows x this cg's 64 cols (LDS broadcast within rg-group)
      float a0 = 0.f, a1 = 0.f, a2 = 0.f, a3 = 0.f;
      const float2* hb2 = (const float2*)(hbuf[c] + cg * 68);
#pragma unroll
      for (int i = 0; i < 32; ++i) {
        float2 h2 = hb2[i];
        unsigned int p0 = pk[0][i], p1 = pk[1][i], p2 = pk[2][i], p3 = pk[3][i];
        a0 += bflo(p0) * h2.x + bfhi(p0) * h2.y;
        a1 += bflo(p1) * h2.x + bfhi(p1) * h2.y;
        a2 += bflo(p2) * h2.x + bfhi(p2) * h2.y;
        a3 += bflo(p3) * h2.x + bfhi(p3) * h2.y;
      }
#pragma unroll
      for (int m = 8; m < 64; m <<= 1) {    // reduce over cg (lane bits 3-5)
        a0 += __shfl_xor(a0, m); a1 += __shfl_xor(a1, m);
        a2 += __shfl_xor(a2, m); a3 += __shfl_xor(a3, m);
      }
      // gates in-lane (replicated across cg; same inputs -> same results)
      float gi = a0 + gin0, gf = a1 + gin1, gg = a2 + gin2, go = a3 + gin3;
      gi = 1.f / (1.f + __expf(-gi));
      gf = 1.f / (1.f + __expf(-gf));
      gg = 1.f - 2.f / (__expf(2.f * gg) + 1.f);     // overflow-safe tanh
      go = 1.f / (1.f + __expf(-go));
      cst[c] = gf * cst[c] + gi * gg;
      float th = 1.f - 2.f / (__expf(2.f * cst[c]) + 1.f);
      float hval = go * th;
      if (lane < 8) {                  // cg==0 lanes store their unit's h
        float* dst = (ls < Wcc)
            ? (wbuf + (ls & 1) * HALF + wgd * 64 + u)
            : (hs_d + (size_t)t * HALF + wgd * 64 + u);
        __hip_atomic_store(dst, hval, __ATOMIC_RELAXED, __HIP_MEMORY_SCOPE_AGENT);
      }
      pend = flg + (size_t)ls * WPC + wgd;   // publish after next barrier
    }
  }
}

// ---------------- phase 3: tag feature GEMM --------------------------------
__global__ __launch_bounds__(256) void feats_kernel(
    const float* __restrict__ hs, const float* __restrict__ Wtag,
    const float* __restrict__ btag, float* __restrict__ feats)
{
  __shared__ float hc[8][257];
  __shared__ float wt[32][257];
  const int tid = threadIdx.x;
  const int t0 = blockIdx.x * 8;
  const int lt = tid >> 5, s = tid & 31;
  float acc = 0.f;
  for (int mc = 0; mc < 1024; mc += 256) {
#pragma unroll
    for (int n = 0; n < 8; ++n) {
      int idx = n * 256 + tid;
      int r = idx >> 8, m = idx & 255;
      int gm = mc + m;
      hc[r][m] = (gm < 512) ? hs[(size_t)(t0 + r) * HALF + gm]
                            : hs[(size_t)(S_LEN + t0 + r) * HALF + (gm - 512)];
    }
#pragma unroll
    for (int n = 0; n < 32; ++n) {
      int idx = n * 256 + tid;
      int r = idx >> 8, m = idx & 255;
      wt[r][m] = Wtag[(size_t)r * 1024 + mc + m];
    }
    __syncthreads();
#pragma unroll 8
    for (int m = 0; m < 256; ++m) acc += hc[lt][m] * wt[s][m];
    __syncthreads();
  }
  feats[(size_t)(t0 + lt) * TAGS + s] = acc + btag[s];
}

// ---------------- phase 4: Viterbi (max-plus block scan) -------------------
__device__ __forceinline__ float featld(const float* __restrict__ feats, int t, int i) {
  return (i < TAGS) ? feats[(size_t)t * TAGS + i] : NEGV;
}

__global__ __launch_bounds__(256) void vit_pass1(
    const float* __restrict__ feats, const float* __restrict__ trans,
    float* __restrict__ P)
{
  const int chain = blockIdx.x * 4 + (threadIdx.x >> 6);
  const int b = chain / ALLT;
  const int k = chain - b * ALLT;
  const int i = threadIdx.x & 63;
  float Trow[ALLT];
#pragma unroll
  for (int j = 0; j < ALLT; ++j)
    Trow[j] = (i < ALLT) ? trans[i * ALLT + j] : -1e30f;
  const int t0 = b * VL;
  float v = (i < ALLT) ? Trow[k] + featld(feats, t0, i) : -1e30f;
  float fn = featld(feats, t0 + 1, i);
  for (int idx = 1; idx < VL; ++idx) {
    float fcur = fn;
    fn = (idx < VL - 1) ? featld(feats, t0 + idx + 1, i) : 0.f;
    float m = -3.4e38f;
#pragma unroll
    for (int j = 0; j < ALLT; ++j) m = fmaxf(m, __shfl(v, j) + Trow[j]);
    v = (i < ALLT) ? m + fcur : -1e30f;
  }
  if (i < ALLT) P[((size_t)b * ALLT + i) * ALLT + k] = v;
}

__global__ __launch_bounds__(64) void vit_pass2(
    const float* __restrict__ P, float* __restrict__ Fb)
{
  const int i = threadIdx.x;
  float F = (i == START_T) ? 0.f : ((i < ALLT) ? NEGV : -1e30f);
  for (int b = 0; b < VB; ++b) {
    if (i < ALLT) Fb[b * ALLT + i] = F;
    float pr[ALLT];
#pragma unroll
    for (int j = 0; j < ALLT; ++j)
      pr[j] = (i < ALLT) ? P[((size_t)b * ALLT + i) * ALLT + j] : -1e30f;
    float m = -3.4e38f;
#pragma unroll
    for (int j = 0; j < ALLT; ++j) m = fmaxf(m, pr[j] + __shfl(F, j));
    F = (i < ALLT) ? m : -1e30f;
  }
}

__global__ __launch_bounds__(64) void vit_pass3(
    const float* __restrict__ feats, const float* __restrict__ trans,
    const float* __restrict__ Fb, int* __restrict__ bp, int* __restrict__ Gmap,
    float* __restrict__ out, int* __restrict__ lastT)
{
  const int b = blockIdx.x;
  const int i = threadIdx.x;
  float Trow[ALLT];
#pragma unroll
  for (int j = 0; j < ALLT; ++j)
    Trow[j] = (i < ALLT) ? trans[i * ALLT + j] : -1e30f;
  float fv = (i < ALLT) ? Fb[b * ALLT + i] : -1e30f;
  int G = 0;
  const int t0 = b * VL;
  float fn = featld(feats, t0, i);
  for (int idx = 0; idx < VL; ++idx) {
    const int t = t0 + idx;
    float fcur = fn;
    fn = (idx < VL - 1) ? featld(feats, t + 1, i) : 0.f;
    float best = -3.4e38f; int bj = 0;
#pragma unroll
    for (int j = 0; j < ALLT; ++j) {
      float sc = __shfl(fv, j) + Trow[j];
      if (sc > best) { best = sc; bj = j; }
    }
    if (i < ALLT) bp[(size_t)t * ALLT + i] = bj;
    int bjc = (i < ALLT) ? bj : 0;
    G = (idx == 0) ? bjc : __shfl(G, bjc);
    fv = (i < ALLT) ? best + fcur : -1e30f;
  }
  if (i < ALLT) Gmap[b * ALLT + i] = G;
  if (b == VB - 1) {
    float term = (i < ALLT) ? fv + trans[STOP_T * ALLT + i] : -3.4e38f;
    int idxl = i;
#pragma unroll
    for (int off = 32; off > 0; off >>= 1) {
      float v2 = __shfl_xor(term, off);
      int i2 = __shfl_xor(idxl, off);
      if (v2 > term || (v2 == term && i2 < idxl)) { term = v2; idxl = i2; }
    }
    if (i == 0) { out[0] = term; *lastT = idxl; }
  }
}

__global__ __launch_bounds__(64) void vit_echain(
    const int* __restrict__ Gmap, const int* __restrict__ lastT,
    int* __restrict__ eb)
{
  __shared__ int sG[VB * ALLT];
  for (int idx = threadIdx.x; idx < VB * ALLT; idx += 64) sG[idx] = Gmap[idx];
  __syncthreads();
  if (threadIdx.x == 0) {
    int tag = *lastT;
    eb[VB - 1] = tag;
    for (int b = VB - 1; b > 0; --b) { tag = sG[b * ALLT + tag]; eb[b - 1] = tag; }
  }
}

__global__ __launch_bounds__(64) void vit_expand(
    const int* __restrict__ bp, const int* __restrict__ eb,
    float* __restrict__ out)
{
  const int b = blockIdx.x;
  __shared__ int lbp[VL * ALLT];
  for (int idx = threadIdx.x; idx < VL * ALLT; idx += 64)
    lbp[idx] = bp[(size_t)b * VL * ALLT + idx];
  __syncthreads();
  if (threadIdx.x == 0) {
    int tag = eb[b];
    for (int i = VL - 1; i >= 0; --i) {
      out[1 + b * VL + i] = (float)tag;
      tag = lbp[i * ALLT + tag];
    }
  }
}

// ---------------------------------------------------------------------------
extern "C" void kernel_launch(void* const* d_in, const int* in_sizes, int n_in,
                              void* d_out, int out_size, void* d_ws, size_t ws_size,
                              hipStream_t stream) {
  (void)in_sizes; (void)n_in; (void)out_size; (void)ws_size;
  const int*   sent  = (const int*)d_in[0];
  const float* emb   = (const float*)d_in[2];
  const float* Wih_f = (const float*)d_in[3];
  const float* Whh_f = (const float*)d_in[4];
  const float* bih_f = (const float*)d_in[5];
  const float* bhh_f = (const float*)d_in[6];
  const float* Wih_b = (const float*)d_in[7];
  const float* Whh_b = (const float*)d_in[8];
  const float* bih_b = (const float*)d_in[9];
  const float* bhh_b = (const float*)d_in[10];
  const float* Wtag  = (const float*)d_in[11];
  const float* btag  = (const float*)d_in[12];
  const float* trans = (const float*)d_in[13];
  const float* h0    = (const float*)d_in[14];
  const float* c0    = (const float*)d_in[15];
  float* out = (float*)d_out;

  // workspace layout; viterbi scratch aliases regions dead by the time it
  // runs: P/Fb/Gmap/eb/lastT in Gin space; bp over hwarm+flags (both dead).
  char* ws = (char*)d_ws;
  float* Gin   = (float*)(ws);                       // 64 MiB
  float* P     = (float*)(ws);                       // 295936 (after lstm)
  float* Fbnd  = (float*)(ws + 1048576);
  int*   Gmap  = (int*)  (ws + 2097152);
  int*   eb    = (int*)  (ws + 3145728);
  int*   lastT = (int*)  (ws + 3146240);
  float* hs    = (float*)(ws + 67108864);            // 16 MiB
  float* feats = (float*)(ws + 83886080);            // 512 KiB
  float* hwarm = (float*)(ws + 84410368);            // 128*2*512*4 = 512 KiB
  unsigned char* flagsB = (unsigned char*)(ws + 84934656);  // 128*128*8 = 128 KiB
  int*   bp    = (int*)  (ws + 84410368);            // 557056, aliases hwarm+flags

  hipMemsetAsync(flagsB, 0, NCHAINS * CLEN * WPC, stream);

  dim3 g1(64, 64);
  ingemm_kernel<<<g1, 256, 0, stream>>>(sent, emb, Wih_f, bih_f, bhh_f,
                                        Wih_b, bih_b, bhh_b, Gin);
  lstm_kernel<<<256, 512, 0, stream>>>(Whh_f, Whh_b, h0, c0, Gin, hs, hwarm, flagsB);
  feats_kernel<<<512, 256, 0, stream>>>(hs, Wtag, btag, feats);
  vit_pass1<<<544, 256, 0, stream>>>(feats, trans, P);
  vit_pass2<<<1, 64, 0, stream>>>(P, Fbnd);
  vit_pass3<<<64, 64, 0, stream>>>(feats, trans, Fbnd, bp, Gmap, out, lastT);
  vit_echain<<<1, 64, 0, stream>>>(Gmap, lastT, eb);
  vit_expand<<<64, 64, 0, stream>>>(bp, eb, out);
}